// Round 18
// baseline (221.872 us; speedup 1.0000x reference)
//
#include <hip/hip_runtime.h>
#include <stdint.h>

#define N_NODES 16384
#define DIM     256
#define KSEL    8192

// ---------------------------------------------------------------------------
// Exact port of Eigen/Cephes pexp<float> (FMA form) — XLA:CPU's f32 exp.
// ---------------------------------------------------------------------------
__device__ __forceinline__ float eigen_pexp_f32(float _x)
{
    float x = fminf(fmaxf(_x, -88.0f), 88.0f);
    float m = floorf(__fmaf_rn(x, 1.44269504088896341f, 0.5f));
    float r = __fmaf_rn(m, -0.693359375f, x);
    r = __fmaf_rn(m, 2.12194440e-4f, r);
    float r2 = __fmul_rn(r, r);
    float y = 1.9875691500e-4f;
    y = __fmaf_rn(y, r, 1.3981999507e-3f);
    y = __fmaf_rn(y, r, 8.3334519073e-3f);
    y = __fmaf_rn(y, r, 4.1665795894e-2f);
    y = __fmaf_rn(y, r, 1.6666665459e-1f);
    y = __fmaf_rn(y, r, 5.0000001201e-1f);
    y = __fmaf_rn(y, r2, r);
    y = __fadd_rn(y, 1.0f);
    return ldexpf(y, (int)m);
}

// ---------------------------------------------------------------------------
// K1: passing-R16 numerics, 8 lanes/row: lane l owns chain k≡l mod 8
// (ascending FMA), then LLVM halves-fold tree via __shfl_xor(4,2,1) —
// bit-identical keys. Also zeroes ranks[].
// ---------------------------------------------------------------------------
__global__ __launch_bounds__(256) void score_kernel(
    const float* __restrict__ x, const float* __restrict__ W,
    const float* __restrict__ b, float* __restrict__ scores,
    unsigned long long* __restrict__ keys, int* __restrict__ ranks)
{
    const int tid = blockIdx.x * 256 + threadIdx.x;
    const int row = tid >> 3;
    const int l   = tid & 7;

    const float* xr = x + (size_t)row * DIM;
    float a = 0.0f;
    #pragma unroll 8
    for (int it = 0; it < DIM / 8; ++it)
        a = __fmaf_rn(xr[it * 8 + l], W[it * 8 + l], a);

    const float s   = __fadd_rn(a, __shfl_xor(a, 4, 64));
    const float t   = __fadd_rn(s, __shfl_xor(s, 2, 64));
    const float dot = __fadd_rn(t, __shfl_xor(t, 1, 64));

    if (l == 0) {
        const float z = __fadd_rn(dot, b[0]);
        const float e = eigen_pexp_f32(-z);
        const float sc = __fdiv_rn(1.0f, __fadd_rn(1.0f, e));
        scores[row] = sc;
        keys[row] = ((unsigned long long)__float_as_uint(sc) << 32)
                  | (unsigned long long)(0xFFFFFFFFu - (unsigned)row);
        ranks[row] = 0;
    }
}

// ---------------------------------------------------------------------------
// K2: ranks[i] = #{ j : keys[j] > keys[i] }. 2048-key LDS tiles, grid (64,8).
// ---------------------------------------------------------------------------
__global__ __launch_bounds__(256) void rank_kernel(
    const unsigned long long* __restrict__ keys, int* __restrict__ ranks)
{
    __shared__ ulonglong2 sk2[1024];
    const int j0 = blockIdx.y * 2048;
    for (int t = threadIdx.x; t < 1024; t += 256)
        sk2[t] = reinterpret_cast<const ulonglong2*>(keys)[j0 / 2 + t];
    __syncthreads();

    const int i = blockIdx.x * 256 + threadIdx.x;
    const unsigned long long ki = keys[i];
    int cnt = 0;
    #pragma unroll 8
    for (int j = 0; j < 1024; ++j) {
        const ulonglong2 k2 = sk2[j];
        cnt += (k2.x > ki) ? 1 : 0;
        cnt += (k2.y > ki) ? 1 : 0;
    }
    if (cnt) atomicAdd(&ranks[i], cnt);
}

// ---------------------------------------------------------------------------
// K3: scatter top-k: rank < K -> position rank.
// ---------------------------------------------------------------------------
__global__ __launch_bounds__(256) void scatter_kernel(
    const int* __restrict__ ranks, const float* __restrict__ scores,
    int* __restrict__ idxs, float* __restrict__ vs, float* __restrict__ out_idx)
{
    const int i = blockIdx.x * 256 + threadIdx.x;
    const int r = ranks[i];
    if (r < KSEL) {
        idxs[r]    = i;
        vs[r]      = scores[i];
        out_idx[r] = (float)i;
    }
}

// ---------------------------------------------------------------------------
// K3b: compaction (1 block): sorted_sel[t] = t-th selected index (ascending
// by index value), pos[i] = its slot. 256 threads x 64 elements + LDS scan.
// ---------------------------------------------------------------------------
__global__ __launch_bounds__(256) void compact_kernel(
    const int* __restrict__ ranks, int* __restrict__ pos,
    int* __restrict__ sorted_sel)
{
    __shared__ int csum[256];
    const int tid = threadIdx.x;
    int cnt = 0;
    for (int j = 0; j < 64; ++j)
        cnt += (ranks[tid * 64 + j] < KSEL) ? 1 : 0;
    csum[tid] = cnt;
    __syncthreads();
    for (int off = 1; off < 256; off <<= 1) {
        const int v = (tid >= off) ? csum[tid - off] : 0;
        __syncthreads();
        csum[tid] += v;
        __syncthreads();
    }
    int base = csum[tid] - cnt;   // exclusive prefix
    for (int j = 0; j < 64; ++j) {
        const int i = tid * 64 + j;
        if (ranks[i] < KSEL) { sorted_sel[base] = i; pos[i] = base; ++base; }
    }
}

// K3c: perm[c] = staged slot of output column c (same for every row).
__global__ __launch_bounds__(256) void perm_kernel(
    const int* __restrict__ idxs, const int* __restrict__ pos,
    int* __restrict__ perm)
{
    const int c = blockIdx.x * 256 + threadIdx.x;
    perm[c] = pos[idxs[c]];
}

// ---------------------------------------------------------------------------
// K4: x_pooled[r,:] = x[idxs[r],:] * vs[r]. One wave per output row.
// ---------------------------------------------------------------------------
__global__ __launch_bounds__(256) void xpool_kernel(
    const float* __restrict__ x, const int* __restrict__ idxs,
    const float* __restrict__ vs, float* __restrict__ outx)
{
    const int wave = (blockIdx.x * 256 + threadIdx.x) >> 6;
    const int lane = threadIdx.x & 63;
    const int row  = idxs[wave];
    const float v  = vs[wave];
    const float4 xv = *reinterpret_cast<const float4*>(x + (size_t)row * DIM + lane * 4);
    float4 o;
    o.x = xv.x * v; o.y = xv.y * v; o.z = xv.z * v; o.w = xv.w * v;
    *reinterpret_cast<float4*>(outx + (size_t)wave * DIM + lane * 4) = o;
}

// ---------------------------------------------------------------------------
// K5 v2: stage ONLY the selected columns (32 KiB, sorted order) via
// global_load_lds width-4 with per-lane gather addresses (LDS dest linear).
// Sorted order -> ascending addresses (~stride-2) -> ~8 line-transactions
// per instr; every 64B line of the row still fetched exactly once.
// 32 KiB LDS -> 5 blocks/CU (was 2) -> read/write phase interleave.
// Output: out[c] = staged[perm[c]]^2, coalesced float4 stores.
// ---------------------------------------------------------------------------
__global__ __launch_bounds__(256) void apool_kernel(
    const float* __restrict__ A, const int* __restrict__ idxs,
    const int* __restrict__ sorted_sel, const int* __restrict__ perm,
    float* __restrict__ outA)
{
    __shared__ float st[KSEL];                        // 32 KiB
    const int r    = blockIdx.x;
    const int src  = idxs[r];
    const int wid  = threadIdx.x >> 6;
    const int lane = threadIdx.x & 63;
    const float* arow = A + (size_t)src * N_NODES;

    int cols[32];                                     // this wave's slots
    #pragma unroll
    for (int c = 0; c < 32; ++c)
        cols[c] = sorted_sel[wid * 2048 + c * 64 + lane];

    #pragma unroll
    for (int c = 0; c < 32; ++c) {
        const float* gsrc = arow + cols[c];           // per-lane gather src
        float* ldst = &st[wid * 2048 + c * 64];       // wave-uniform dest
        __builtin_amdgcn_global_load_lds(
            (const __attribute__((address_space(1))) void*)gsrc,
            (__attribute__((address_space(3))) void*)ldst,
            4, 0, 0);
    }
    __syncthreads();

    float* orow = outA + (size_t)r * KSEL;
    #pragma unroll
    for (int it = 0; it < 8; ++it) {
        const int q = it * 256 + threadIdx.x;
        const int4 p4 = reinterpret_cast<const int4*>(perm)[q];
        float4 o;
        o.x = st[p4.x]; o.y = st[p4.y]; o.z = st[p4.z]; o.w = st[p4.w];
        o.x *= o.x; o.y *= o.y; o.z *= o.z; o.w *= o.w;
        reinterpret_cast<float4*>(orow)[q] = o;
    }
}

// ---------------------------------------------------------------------------
extern "C" void kernel_launch(void* const* d_in, const int* in_sizes, int n_in,
                              void* d_out, int out_size, void* d_ws, size_t ws_size,
                              hipStream_t stream)
{
    const float* A = (const float*)d_in[0];
    const float* x = (const float*)d_in[1];
    const float* W = (const float*)d_in[2];
    const float* b = (const float*)d_in[3];
    (void)in_sizes; (void)n_in; (void)out_size; (void)ws_size;

    char* ws = (char*)d_ws;
    unsigned long long* keys = (unsigned long long*)(ws);           // 128 KiB
    int*    ranks  = (int*)   (ws + 131072);                        //  64 KiB
    float*  scores = (float*) (ws + 196608);                        //  64 KiB
    int*    idxs   = (int*)   (ws + 262144);                        //  32 KiB
    float*  vs     = (float*) (ws + 294912);                        //  32 KiB
    int*    pos    = (int*)   (ws + 327680);                        //  64 KiB
    int*    ssel   = (int*)   (ws + 393216);                        //  32 KiB
    int*    perm   = (int*)   (ws + 425984);                        //  32 KiB

    float* outA = (float*)d_out;                                    // (K,K)
    float* outX = outA + (size_t)KSEL * KSEL;                       // (K,D)
    float* outI = outX + (size_t)KSEL * DIM;                        // (K,)

    score_kernel<<<N_NODES * 8 / 256, 256, 0, stream>>>(x, W, b, scores, keys, ranks);
    dim3 rgrid(N_NODES / 256, 8);
    rank_kernel<<<rgrid, 256, 0, stream>>>(keys, ranks);
    scatter_kernel<<<N_NODES / 256, 256, 0, stream>>>(ranks, scores, idxs, vs, outI);
    compact_kernel<<<1, 256, 0, stream>>>(ranks, pos, ssel);
    perm_kernel<<<KSEL / 256, 256, 0, stream>>>(idxs, pos, perm);
    xpool_kernel<<<KSEL / 4, 256, 0, stream>>>(x, idxs, vs, outX);
    apool_kernel<<<KSEL, 256, 0, stream>>>(A, idxs, ssel, perm, outA);
}

// Round 19
// 199.799 us; speedup vs baseline: 1.1105x; 1.1105x over previous
//
#include <hip/hip_runtime.h>
#include <stdint.h>

#define N_NODES 16384
#define DIM     256
#define KSEL    8192

// ---------------------------------------------------------------------------
// Exact port of Eigen/Cephes pexp<float> (FMA form) — XLA:CPU's f32 exp.
// ---------------------------------------------------------------------------
__device__ __forceinline__ float eigen_pexp_f32(float _x)
{
    float x = fminf(fmaxf(_x, -88.0f), 88.0f);
    float m = floorf(__fmaf_rn(x, 1.44269504088896341f, 0.5f));
    float r = __fmaf_rn(m, -0.693359375f, x);
    r = __fmaf_rn(m, 2.12194440e-4f, r);
    float r2 = __fmul_rn(r, r);
    float y = 1.9875691500e-4f;
    y = __fmaf_rn(y, r, 1.3981999507e-3f);
    y = __fmaf_rn(y, r, 8.3334519073e-3f);
    y = __fmaf_rn(y, r, 4.1665795894e-2f);
    y = __fmaf_rn(y, r, 1.6666665459e-1f);
    y = __fmaf_rn(y, r, 5.0000001201e-1f);
    y = __fmaf_rn(y, r2, r);
    y = __fadd_rn(y, 1.0f);
    return ldexpf(y, (int)m);
}

// ---------------------------------------------------------------------------
// K1: passing-R16 numerics, 8 lanes/row (bit-identical keys). Zeroes ranks[].
// ---------------------------------------------------------------------------
__global__ __launch_bounds__(256) void score_kernel(
    const float* __restrict__ x, const float* __restrict__ W,
    const float* __restrict__ b, float* __restrict__ scores,
    unsigned long long* __restrict__ keys, int* __restrict__ ranks)
{
    const int tid = blockIdx.x * 256 + threadIdx.x;
    const int row = tid >> 3;
    const int l   = tid & 7;

    const float* xr = x + (size_t)row * DIM;
    float a = 0.0f;
    #pragma unroll 8
    for (int it = 0; it < DIM / 8; ++it)
        a = __fmaf_rn(xr[it * 8 + l], W[it * 8 + l], a);

    const float s   = __fadd_rn(a, __shfl_xor(a, 4, 64));
    const float t   = __fadd_rn(s, __shfl_xor(s, 2, 64));
    const float dot = __fadd_rn(t, __shfl_xor(t, 1, 64));

    if (l == 0) {
        const float z = __fadd_rn(dot, b[0]);
        const float e = eigen_pexp_f32(-z);
        const float sc = __fdiv_rn(1.0f, __fadd_rn(1.0f, e));
        scores[row] = sc;
        keys[row] = ((unsigned long long)__float_as_uint(sc) << 32)
                  | (unsigned long long)(0xFFFFFFFFu - (unsigned)row);
        ranks[row] = 0;
    }
}

// ---------------------------------------------------------------------------
// K2: ranks[i] = #{ j : keys[j] > keys[i] }. 2048-key LDS tiles, grid (64,8).
// ---------------------------------------------------------------------------
__global__ __launch_bounds__(256) void rank_kernel(
    const unsigned long long* __restrict__ keys, int* __restrict__ ranks)
{
    __shared__ ulonglong2 sk2[1024];
    const int j0 = blockIdx.y * 2048;
    for (int t = threadIdx.x; t < 1024; t += 256)
        sk2[t] = reinterpret_cast<const ulonglong2*>(keys)[j0 / 2 + t];
    __syncthreads();

    const int i = blockIdx.x * 256 + threadIdx.x;
    const unsigned long long ki = keys[i];
    int cnt = 0;
    #pragma unroll 8
    for (int j = 0; j < 1024; ++j) {
        const ulonglong2 k2 = sk2[j];
        cnt += (k2.x > ki) ? 1 : 0;
        cnt += (k2.y > ki) ? 1 : 0;
    }
    if (cnt) atomicAdd(&ranks[i], cnt);
}

// ---------------------------------------------------------------------------
// K3: scatter top-k: rank < K -> position rank.
// ---------------------------------------------------------------------------
__global__ __launch_bounds__(256) void scatter_kernel(
    const int* __restrict__ ranks, const float* __restrict__ scores,
    int* __restrict__ idxs, float* __restrict__ vs, float* __restrict__ out_idx)
{
    const int i = blockIdx.x * 256 + threadIdx.x;
    const int r = ranks[i];
    if (r < KSEL) {
        idxs[r]    = i;
        vs[r]      = scores[i];
        out_idx[r] = (float)i;
    }
}

// ---------------------------------------------------------------------------
// K4: x_pooled[r,:] = x[idxs[r],:] * vs[r]. One wave per output row.
// ---------------------------------------------------------------------------
__global__ __launch_bounds__(256) void xpool_kernel(
    const float* __restrict__ x, const int* __restrict__ idxs,
    const float* __restrict__ vs, float* __restrict__ outx)
{
    const int wave = (blockIdx.x * 256 + threadIdx.x) >> 6;
    const int lane = threadIdx.x & 63;
    const int row  = idxs[wave];
    const float v  = vs[wave];
    const float4 xv = *reinterpret_cast<const float4*>(x + (size_t)row * DIM + lane * 4);
    float4 o;
    o.x = xv.x * v; o.y = xv.y * v; o.z = xv.z * v; o.w = xv.w * v;
    *reinterpret_cast<float4*>(outx + (size_t)wave * DIM + lane * 4) = o;
}

// ---------------------------------------------------------------------------
// K5 v3: persistent double-buffered. 512 blocks x 512 threads, LDS
// buf[2][16384] (128 KiB -> 1 block/CU, 8 waves). Each block owns rows
// {b, 512+b, ..., 15*512+b}. Per iteration:
//   barrier (drains prev stage's vmcnt -> buf[cur] ready)
//   issue stage(next row -> buf[cur^1])   [fire-and-forget, after barrier]
//   gather+store current row from buf[cur]
// Next row's 64 KiB of reads are in flight DURING the 32 KiB store phase ->
// read/write pipes overlap within the block (R17's 2-block lockstep didn't).
// Staging is the proven linear width-16 global_load_lds (R17).
// ---------------------------------------------------------------------------
__global__ __launch_bounds__(512) void apool_kernel(
    const float* __restrict__ A, const int* __restrict__ idxs,
    float* __restrict__ outA)
{
    __shared__ float buf[2][N_NODES];                 // 2 x 64 KiB
    const int wid  = threadIdx.x >> 6;                // 0..7
    const int lane = threadIdx.x & 63;

    // issue the 64-chunk linear stage of row r into buf[slot]
    #define STAGE(slot, r)                                                   \
        do {                                                                 \
            const int   _src  = idxs[r];                                     \
            const float* _arow = A + (size_t)_src * N_NODES;                 \
            _Pragma("unroll")                                                \
            for (int _c = 0; _c < 8; ++_c) {                                 \
                const int _chunk = wid * 8 + _c;                             \
                const float* _gsrc = _arow + _chunk * 256 + lane * 4;        \
                float* _ldst = &buf[slot][_chunk * 256];                     \
                __builtin_amdgcn_global_load_lds(                            \
                    (const __attribute__((address_space(1))) void*)_gsrc,    \
                    (__attribute__((address_space(3))) void*)_ldst,          \
                    16, 0, 0);                                               \
            }                                                                \
        } while (0)

    int cur = 0;
    STAGE(0, (int)blockIdx.x);
    for (int t = 0; t < 16; ++t) {
        __syncthreads();                              // buf[cur] complete
        if (t + 1 < 16) {
            const int rn = (t + 1) * 512 + blockIdx.x;
            STAGE(cur ^ 1, rn);                       // overlaps store phase
        }
        const int r = t * 512 + blockIdx.x;
        float* orow = outA + (size_t)r * KSEL;
        #pragma unroll
        for (int it = 0; it < 4; ++it) {
            const int q = it * 512 + threadIdx.x;     // float4 index < 2048
            const int4 id4 = reinterpret_cast<const int4*>(idxs)[q];
            float4 o;
            o.x = buf[cur][id4.x]; o.y = buf[cur][id4.y];
            o.z = buf[cur][id4.z]; o.w = buf[cur][id4.w];
            o.x *= o.x; o.y *= o.y; o.z *= o.z; o.w *= o.w;
            reinterpret_cast<float4*>(orow)[q] = o;
        }
        cur ^= 1;
    }
    #undef STAGE
}

// ---------------------------------------------------------------------------
extern "C" void kernel_launch(void* const* d_in, const int* in_sizes, int n_in,
                              void* d_out, int out_size, void* d_ws, size_t ws_size,
                              hipStream_t stream)
{
    const float* A = (const float*)d_in[0];
    const float* x = (const float*)d_in[1];
    const float* W = (const float*)d_in[2];
    const float* b = (const float*)d_in[3];
    (void)in_sizes; (void)n_in; (void)out_size; (void)ws_size;

    char* ws = (char*)d_ws;
    unsigned long long* keys = (unsigned long long*)(ws);           // 128 KiB
    int*    ranks  = (int*)   (ws + 131072);                        //  64 KiB
    float*  scores = (float*) (ws + 196608);                        //  64 KiB
    int*    idxs   = (int*)   (ws + 262144);                        //  32 KiB
    float*  vs     = (float*) (ws + 294912);                        //  32 KiB

    float* outA = (float*)d_out;                                    // (K,K)
    float* outX = outA + (size_t)KSEL * KSEL;                       // (K,D)
    float* outI = outX + (size_t)KSEL * DIM;                        // (K,)

    score_kernel<<<N_NODES * 8 / 256, 256, 0, stream>>>(x, W, b, scores, keys, ranks);
    dim3 rgrid(N_NODES / 256, 8);
    rank_kernel<<<rgrid, 256, 0, stream>>>(keys, ranks);
    scatter_kernel<<<N_NODES / 256, 256, 0, stream>>>(ranks, scores, idxs, vs, outI);
    xpool_kernel<<<KSEL / 4, 256, 0, stream>>>(x, idxs, vs, outX);
    apool_kernel<<<512, 512, 0, stream>>>(A, idxs, outA);
}

// Round 20
// 197.590 us; speedup vs baseline: 1.1229x; 1.0112x over previous
//
#include <hip/hip_runtime.h>
#include <stdint.h>

#define N_NODES 16384
#define DIM     256
#define KSEL    8192

// ---------------------------------------------------------------------------
// Exact port of Eigen/Cephes pexp<float> (FMA form) — XLA:CPU's f32 exp.
// ---------------------------------------------------------------------------
__device__ __forceinline__ float eigen_pexp_f32(float _x)
{
    float x = fminf(fmaxf(_x, -88.0f), 88.0f);
    float m = floorf(__fmaf_rn(x, 1.44269504088896341f, 0.5f));
    float r = __fmaf_rn(m, -0.693359375f, x);
    r = __fmaf_rn(m, 2.12194440e-4f, r);
    float r2 = __fmul_rn(r, r);
    float y = 1.9875691500e-4f;
    y = __fmaf_rn(y, r, 1.3981999507e-3f);
    y = __fmaf_rn(y, r, 8.3334519073e-3f);
    y = __fmaf_rn(y, r, 4.1665795894e-2f);
    y = __fmaf_rn(y, r, 1.6666665459e-1f);
    y = __fmaf_rn(y, r, 5.0000001201e-1f);
    y = __fmaf_rn(y, r2, r);
    y = __fadd_rn(y, 1.0f);
    return ldexpf(y, (int)m);
}

// ---------------------------------------------------------------------------
// K1: passing-R16 numerics, 8 lanes/row (bit-identical keys). Zeroes ranks[].
// ---------------------------------------------------------------------------
__global__ __launch_bounds__(256) void score_kernel(
    const float* __restrict__ x, const float* __restrict__ W,
    const float* __restrict__ b, float* __restrict__ scores,
    unsigned long long* __restrict__ keys, int* __restrict__ ranks)
{
    const int tid = blockIdx.x * 256 + threadIdx.x;
    const int row = tid >> 3;
    const int l   = tid & 7;

    const float* xr = x + (size_t)row * DIM;
    float a = 0.0f;
    #pragma unroll 8
    for (int it = 0; it < DIM / 8; ++it)
        a = __fmaf_rn(xr[it * 8 + l], W[it * 8 + l], a);

    const float s   = __fadd_rn(a, __shfl_xor(a, 4, 64));
    const float t   = __fadd_rn(s, __shfl_xor(s, 2, 64));
    const float dot = __fadd_rn(t, __shfl_xor(t, 1, 64));

    if (l == 0) {
        const float z = __fadd_rn(dot, b[0]);
        const float e = eigen_pexp_f32(-z);
        const float sc = __fdiv_rn(1.0f, __fadd_rn(1.0f, e));
        scores[row] = sc;
        keys[row] = ((unsigned long long)__float_as_uint(sc) << 32)
                  | (unsigned long long)(0xFFFFFFFFu - (unsigned)row);
        ranks[row] = 0;
    }
}

// ---------------------------------------------------------------------------
// K2: ranks[i] = #{ j : keys[j] > keys[i] }. 2048-key LDS tiles, grid (64,8).
// ---------------------------------------------------------------------------
__global__ __launch_bounds__(256) void rank_kernel(
    const unsigned long long* __restrict__ keys, int* __restrict__ ranks)
{
    __shared__ ulonglong2 sk2[1024];
    const int j0 = blockIdx.y * 2048;
    for (int t = threadIdx.x; t < 1024; t += 256)
        sk2[t] = reinterpret_cast<const ulonglong2*>(keys)[j0 / 2 + t];
    __syncthreads();

    const int i = blockIdx.x * 256 + threadIdx.x;
    const unsigned long long ki = keys[i];
    int cnt = 0;
    #pragma unroll 8
    for (int j = 0; j < 1024; ++j) {
        const ulonglong2 k2 = sk2[j];
        cnt += (k2.x > ki) ? 1 : 0;
        cnt += (k2.y > ki) ? 1 : 0;
    }
    if (cnt) atomicAdd(&ranks[i], cnt);
}

// ---------------------------------------------------------------------------
// K3: scatter top-k: rank < K -> position rank.
// ---------------------------------------------------------------------------
__global__ __launch_bounds__(256) void scatter_kernel(
    const int* __restrict__ ranks, const float* __restrict__ scores,
    int* __restrict__ idxs, float* __restrict__ vs, float* __restrict__ out_idx)
{
    const int i = blockIdx.x * 256 + threadIdx.x;
    const int r = ranks[i];
    if (r < KSEL) {
        idxs[r]    = i;
        vs[r]      = scores[i];
        out_idx[r] = (float)i;
    }
}

// ---------------------------------------------------------------------------
// K5 v4 (R17 structure, widened + fused): one block per output row,
// 512 threads (8 waves), single 64 KiB LDS row buffer -> 2 blocks/CU,
// 16 waves/CU. Stage = 8 linear width-16 global_load_lds per wave (proven
// R17 path, half the per-wave chain of R17). While staging is in flight,
// wave 0 computes the fused x_pooled row (1 KiB r/w). Barrier (full drain)
// then gather+square+coalesced stores.
// ---------------------------------------------------------------------------
__global__ __launch_bounds__(512) void apool_kernel(
    const float* __restrict__ A, const int* __restrict__ idxs,
    const float* __restrict__ x, const float* __restrict__ vs,
    float* __restrict__ outA, float* __restrict__ outX)
{
    __shared__ float row[N_NODES];                    // 64 KiB
    const int r    = blockIdx.x;
    const int src  = idxs[r];
    const int wid  = threadIdx.x >> 6;                // 0..7
    const int lane = threadIdx.x & 63;
    const float* arow = A + (size_t)src * N_NODES;

    #pragma unroll
    for (int c = 0; c < 8; ++c) {
        const int chunk = wid * 8 + c;                // 64 chunks of 256 floats
        const float* gsrc = arow + chunk * 256 + lane * 4;
        float* ldst = &row[chunk * 256];              // wave-uniform dest
        __builtin_amdgcn_global_load_lds(
            (const __attribute__((address_space(1))) void*)gsrc,
            (__attribute__((address_space(3))) void*)ldst,
            16, 0, 0);
    }

    // Fused x_pooled row r (independent of LDS; overlaps staging latency).
    if (wid == 0) {
        const float v = vs[r];
        const float4 xv = *reinterpret_cast<const float4*>(
            x + (size_t)src * DIM + lane * 4);
        float4 o;
        o.x = xv.x * v; o.y = xv.y * v; o.z = xv.z * v; o.w = xv.w * v;
        *reinterpret_cast<float4*>(outX + (size_t)r * DIM + lane * 4) = o;
    }
    __syncthreads();                                  // stage complete

    float* orow = outA + (size_t)r * KSEL;
    #pragma unroll
    for (int it = 0; it < 4; ++it) {
        const int q = it * 512 + threadIdx.x;         // float4 index < 2048
        const int4 id4 = reinterpret_cast<const int4*>(idxs)[q];
        float4 o;
        o.x = row[id4.x]; o.y = row[id4.y]; o.z = row[id4.z]; o.w = row[id4.w];
        o.x *= o.x; o.y *= o.y; o.z *= o.z; o.w *= o.w;
        reinterpret_cast<float4*>(orow)[q] = o;
    }
}

// ---------------------------------------------------------------------------
extern "C" void kernel_launch(void* const* d_in, const int* in_sizes, int n_in,
                              void* d_out, int out_size, void* d_ws, size_t ws_size,
                              hipStream_t stream)
{
    const float* A = (const float*)d_in[0];
    const float* x = (const float*)d_in[1];
    const float* W = (const float*)d_in[2];
    const float* b = (const float*)d_in[3];
    (void)in_sizes; (void)n_in; (void)out_size; (void)ws_size;

    char* ws = (char*)d_ws;
    unsigned long long* keys = (unsigned long long*)(ws);           // 128 KiB
    int*    ranks  = (int*)   (ws + 131072);                        //  64 KiB
    float*  scores = (float*) (ws + 196608);                        //  64 KiB
    int*    idxs   = (int*)   (ws + 262144);                        //  32 KiB
    float*  vs     = (float*) (ws + 294912);                        //  32 KiB

    float* outA = (float*)d_out;                                    // (K,K)
    float* outX = outA + (size_t)KSEL * KSEL;                       // (K,D)
    float* outI = outX + (size_t)KSEL * DIM;                        // (K,)

    score_kernel<<<N_NODES * 8 / 256, 256, 0, stream>>>(x, W, b, scores, keys, ranks);
    dim3 rgrid(N_NODES / 256, 8);
    rank_kernel<<<rgrid, 256, 0, stream>>>(keys, ranks);
    scatter_kernel<<<N_NODES / 256, 256, 0, stream>>>(ranks, scores, idxs, vs, outI);
    apool_kernel<<<KSEL, 512, 0, stream>>>(A, idxs, x, vs, outA, outX);
}